// Round 8
// baseline (548.655 us; speedup 1.0000x reference)
//
#include <hip/hip_runtime.h>

#define C_ 128
#define N0 16384
#define E0 65024
#define NC_ 1024
#define E1C 3968
#define LSTR 40    // W-tile stride in shorts (80B = 5*16B, odd 16B-units -> uniform slots)
#define HSTR 36    // packed-H stride in u32 (144B = 9*16B, odd)

typedef __attribute__((ext_vector_type(8))) short bf16x8;
typedef __attribute__((ext_vector_type(16))) float f32x16;

// weight table offsets (in shorts) inside the ws bf16 region
#define OFF_WE1 0
#define OFF_WE2 294912
#define OFF_WN1 393216
#define OFF_WN2 589824
#define W_TOTAL 688128

__device__ __forceinline__ void bsplit(float a, unsigned short& hi, unsigned short& lo) {
  unsigned ab = __float_as_uint(a);
  unsigned hb = ab & 0xFFFF0000u;          // truncate to bf16
  hi = (unsigned short)(hb >> 16);
  float r = a - __uint_as_float(hb);       // exact residual
  lo = (unsigned short)(__float_as_uint(r) >> 16);
}

__device__ __forceinline__ int cprefix(int ci, int cj) {
  int rows = (ci == 0) ? 0 : (94 + (ci - 1) * 126);
  int v = (ci > 0) + (ci < 31);
  int within = (cj == 0) ? 0 : (2 * cj - 1);
  return rows + within + cj * v;
}

__device__ __forceinline__ void add4(float4& s, const float* p) {
  float4 v = *(const float4*)p;
  s.x += v.x; s.y += v.y; s.z += v.z; s.w += v.w;
}

__device__ __forceinline__ f32x16 zero16() {
  f32x16 z;
  #pragma unroll
  for (int i = 0; i < 16; ++i) z[i] = 0.f;
  return z;
}

// ---- one-time weight transpose + bf16 hi/lo split: [layer][K/32][128 cols][32 k] ----
__global__ void prep_weights(const float* __restrict__ We1, const float* __restrict__ We2,
                             const float* __restrict__ Wn1, const float* __restrict__ Wn2,
                             short* __restrict__ wh, short* __restrict__ wl) {
  int idx = blockIdx.x * 256 + threadIdx.x;   // < 688128
  const float* src; int Kt, off, rem;
  if (idx < 294912)      { src = We1; Kt = 384; off = OFF_WE1; rem = idx; }
  else if (idx < 393216) { src = We2; Kt = 128; off = OFF_WE2; rem = idx - 294912; }
  else if (idx < 589824) { src = Wn1; Kt = 256; off = OFF_WN1; rem = idx - 393216; }
  else                   { src = Wn2; Kt = 128; off = OFF_WN2; rem = idx - 589824; }
  int per_layer = Kt << 7;
  int layer = rem / per_layer;
  int r2 = rem - layer * per_layer;
  int k = r2 >> 7;
  int col = r2 & 127;
  float a = src[layer * per_layer + (k << 7) + col];
  unsigned short hi, lo;
  bsplit(a, hi, lo);
  int dst = off + layer * ((Kt >> 5) << 12) + ((k >> 5) << 12) + (col << 5) + (k & 31);
  wh[dst] = (short)hi;
  wl[dst] = (short)lo;
}

__device__ __forceinline__ void stage_w(short* sWh, short* sWl,
                                        const short* __restrict__ Wh,
                                        const short* __restrict__ Wl,
                                        int kc, int tid) {
  const short* srcH = Wh + (kc << 12);
  const short* srcL = Wl + (kc << 12);
  #pragma unroll
  for (int u0 = 0; u0 < 2; ++u0) {
    int u = tid + u0 * 256;            // 0..511 16B units (128 cols x 4 parts)
    int col = u >> 2, part = u & 3;
    *(uint4*)&sWh[col * LSTR + part * 8] = *(const uint4*)(srcH + u * 8);
    *(uint4*)&sWl[col * LSTR + part * 8] = *(const uint4*)(srcL + u * 8);
  }
}

#define BSPLIT8(V0, V1, AH, AL) do { \
    unsigned short h0_,h1_,h2_,h3_,h4_,h5_,h6_,h7_, l0_,l1_,l2_,l3_,l4_,l5_,l6_,l7_; \
    bsplit((V0).x,h0_,l0_); bsplit((V0).y,h1_,l1_); bsplit((V0).z,h2_,l2_); bsplit((V0).w,h3_,l3_); \
    bsplit((V1).x,h4_,l4_); bsplit((V1).y,h5_,l5_); bsplit((V1).z,h6_,l6_); bsplit((V1).w,h7_,l7_); \
    AH = (bf16x8){(short)h0_,(short)h1_,(short)h2_,(short)h3_,(short)h4_,(short)h5_,(short)h6_,(short)h7_}; \
    AL = (bf16x8){(short)l0_,(short)l1_,(short)l2_,(short)l3_,(short)l4_,(short)l5_,(short)l6_,(short)l7_}; \
  } while (0)

#define MFMA3(ACC, AH, AL, BH, BL) do { \
    ACC = __builtin_amdgcn_mfma_f32_32x32x16_bf16(AH, BH, ACC, 0, 0, 0); \
    ACC = __builtin_amdgcn_mfma_f32_32x32x16_bf16(AH, BL, ACC, 0, 0, 0); \
    ACC = __builtin_amdgcn_mfma_f32_32x32x16_bf16(AL, BH, ACC, 0, 0, 0); \
  } while (0)

#define UNPACKH(ROW, S, AH, AL) do { \
    const unsigned* hp_ = &sH[(ROW) * HSTR + (S) * 16 + hi * 8]; \
    uint4 u0_ = *(const uint4*)hp_; uint4 u1_ = *(const uint4*)(hp_ + 4); \
    AH = (bf16x8){(short)(u0_.x & 0xFFFFu), (short)(u0_.y & 0xFFFFu), (short)(u0_.z & 0xFFFFu), (short)(u0_.w & 0xFFFFu), \
                  (short)(u1_.x & 0xFFFFu), (short)(u1_.y & 0xFFFFu), (short)(u1_.z & 0xFFFFu), (short)(u1_.w & 0xFFFFu)}; \
    AL = (bf16x8){(short)(u0_.x >> 16), (short)(u0_.y >> 16), (short)(u0_.z >> 16), (short)(u0_.w >> 16), \
                  (short)(u1_.x >> 16), (short)(u1_.y >> 16), (short)(u1_.z >> 16), (short)(u1_.w >> 16)}; \
  } while (0)

// MODE 0: edge MLP, K1=384, A = [e_row | x[src] | x[dst]]
// MODE 1: node MLP, K1=256, A = [x_row | agg_row]
// io = io + relu(A@W1 + b1)@W2 + b2. 128x128 block tile, 4 waves (2x2), 32x32 MFMA,
// bf16 hi/lo split (3 mfma/product). A frags read direct from global (lane=row).
template<int MODE>
__global__ __launch_bounds__(256, 2) void mlp_mfma(
    float* __restrict__ io, const float* __restrict__ xin,
    const int* __restrict__ srcI, const int* __restrict__ dstI,
    const short* __restrict__ W1h, const short* __restrict__ W1l,
    const float* __restrict__ b1,
    const short* __restrict__ W2h, const short* __restrict__ W2l,
    const float* __restrict__ b2)
{
  __shared__ alignas(16) short sWh[128 * LSTR], sWl[128 * LSTR];   // 20.0 KiB
  __shared__ alignas(16) unsigned sH[128 * HSTR];                  // 18.0 KiB (packed hi|lo<<16)

  const int tid = threadIdx.x;
  const int w   = tid >> 6;
  const int wr  = w >> 1;         // row half: rows [wr*64, +64)
  const int wc  = w & 1;          // col half: cols [wc*64, +64)
  const int l   = tid & 63;
  const int c31 = l & 31;
  const int hi  = l >> 5;         // k-subgroup (8 wide)
  const int r0  = blockIdx.x * 128;

  // per-lane A row pointers (lane c31 = fragment row; rt in {0,1})
  const int ar0 = wr * 64 + c31;
  const int ar1 = ar0 + 32;
  const float* pio0 = io + (size_t)(r0 + ar0) * C_;
  const float* pio1 = io + (size_t)(r0 + ar1) * C_;
  const float *px0, *px1, *pd0, *pd1;
  if (MODE == 0) {
    px0 = xin + (size_t)srcI[r0 + ar0] * C_;
    px1 = xin + (size_t)srcI[r0 + ar1] * C_;
    pd0 = xin + (size_t)dstI[r0 + ar0] * C_;
    pd1 = xin + (size_t)dstI[r0 + ar1] * C_;
  } else {
    px0 = xin + (size_t)(r0 + ar0) * C_;
    px1 = xin + (size_t)(r0 + ar1) * C_;
    pd0 = px0; pd1 = px1;  // unused
  }

  float4 pa00, pa01, pa02, pa03, pa10, pa11, pa12, pa13;
#define LOADA(KC) do { \
    int rg_ = (KC) >> 2; int cb_ = ((KC) & 3) * 32 + hi * 8; \
    const float* q0_; const float* q1_; \
    if (MODE == 0) { q0_ = (rg_ == 0) ? pio0 : (rg_ == 1) ? px0 : pd0; \
                     q1_ = (rg_ == 0) ? pio1 : (rg_ == 1) ? px1 : pd1; } \
    else           { q0_ = (rg_ == 0) ? pio0 : px0; \
                     q1_ = (rg_ == 0) ? pio1 : px1; } \
    pa00 = *(const float4*)(q0_ + cb_);      pa01 = *(const float4*)(q0_ + cb_ + 4); \
    pa02 = *(const float4*)(q0_ + cb_ + 16); pa03 = *(const float4*)(q0_ + cb_ + 20); \
    pa10 = *(const float4*)(q1_ + cb_);      pa11 = *(const float4*)(q1_ + cb_ + 4); \
    pa12 = *(const float4*)(q1_ + cb_ + 16); pa13 = *(const float4*)(q1_ + cb_ + 20); \
  } while (0)

  f32x16 acc00 = zero16(), acc01 = zero16(), acc10 = zero16(), acc11 = zero16();

  // ---------------- GEMM1 ----------------
  const int NK1 = (MODE == 0) ? 12 : 8;
  LOADA(0);
  for (int kc = 0; kc < NK1; ++kc) {
    bf16x8 ah0s0, al0s0, ah0s1, al0s1, ah1s0, al1s0, ah1s1, al1s1;
    BSPLIT8(pa00, pa01, ah0s0, al0s0);
    BSPLIT8(pa02, pa03, ah0s1, al0s1);
    BSPLIT8(pa10, pa11, ah1s0, al1s0);
    BSPLIT8(pa12, pa13, ah1s1, al1s1);
    if (kc + 1 < NK1) LOADA(kc + 1);
    __syncthreads();                       // all waves done reading sW chunk kc-1
    stage_w(sWh, sWl, W1h, W1l, kc, tid);
    __syncthreads();                       // sW chunk kc ready
    #pragma unroll
    for (int s = 0; s < 2; ++s) {
      const int wb = s * 16 + hi * 8;
      bf16x8 bh0 = *(const bf16x8*)&sWh[(wc * 64 + c31) * LSTR + wb];
      bf16x8 bl0 = *(const bf16x8*)&sWl[(wc * 64 + c31) * LSTR + wb];
      bf16x8 bh1 = *(const bf16x8*)&sWh[(wc * 64 + 32 + c31) * LSTR + wb];
      bf16x8 bl1 = *(const bf16x8*)&sWl[(wc * 64 + 32 + c31) * LSTR + wb];
      if (s == 0) {
        MFMA3(acc00, ah0s0, al0s0, bh0, bl0);
        MFMA3(acc01, ah0s0, al0s0, bh1, bl1);
        MFMA3(acc10, ah1s0, al1s0, bh0, bl0);
        MFMA3(acc11, ah1s0, al1s0, bh1, bl1);
      } else {
        MFMA3(acc00, ah0s1, al0s1, bh0, bl0);
        MFMA3(acc01, ah0s1, al0s1, bh1, bl1);
        MFMA3(acc10, ah1s1, al1s1, bh0, bl0);
        MFMA3(acc11, ah1s1, al1s1, bh1, bl1);
      }
    }
  }

  // ---------------- GEMM2 (H @ W2), H chunked through sH ----------------
  f32x16 bcc00 = zero16(), bcc01 = zero16(), bcc10 = zero16(), bcc11 = zero16();
  #pragma unroll
  for (int kc = 0; kc < 4; ++kc) {
    __syncthreads();                       // prior sW/sH reads done
    if (wc == (kc >> 1)) {                 // this wave owns H cols [kc*32, +32)
      const float bb = b1[(kc >> 1) * 64 + (kc & 1) * 32 + c31];
      #pragma unroll
      for (int rg = 0; rg < 16; ++rg) {
        int rr = (rg & 3) + 8 * (rg >> 2) + 4 * hi;
        float h0 = fmaxf(((kc & 1) ? acc01[rg] : acc00[rg]) + bb, 0.f);
        float h1 = fmaxf(((kc & 1) ? acc11[rg] : acc10[rg]) + bb, 0.f);
        unsigned short hh, hl;
        bsplit(h0, hh, hl);
        sH[(wr * 64 + rr) * HSTR + c31] = (unsigned)hh | ((unsigned)hl << 16);
        bsplit(h1, hh, hl);
        sH[(wr * 64 + 32 + rr) * HSTR + c31] = (unsigned)hh | ((unsigned)hl << 16);
      }
    }
    stage_w(sWh, sWl, W2h, W2l, kc, tid);
    __syncthreads();                       // sH chunk + sW chunk ready
    #pragma unroll
    for (int s = 0; s < 2; ++s) {
      bf16x8 ah0, al0, ah1, al1;
      UNPACKH(wr * 64 + c31, s, ah0, al0);
      UNPACKH(wr * 64 + 32 + c31, s, ah1, al1);
      const int wb = s * 16 + hi * 8;
      bf16x8 bh0 = *(const bf16x8*)&sWh[(wc * 64 + c31) * LSTR + wb];
      bf16x8 bl0 = *(const bf16x8*)&sWl[(wc * 64 + c31) * LSTR + wb];
      bf16x8 bh1 = *(const bf16x8*)&sWh[(wc * 64 + 32 + c31) * LSTR + wb];
      bf16x8 bl1 = *(const bf16x8*)&sWl[(wc * 64 + 32 + c31) * LSTR + wb];
      MFMA3(bcc00, ah0, al0, bh0, bl0);
      MFMA3(bcc01, ah0, al0, bh1, bl1);
      MFMA3(bcc10, ah1, al1, bh0, bl0);
      MFMA3(bcc11, ah1, al1, bh1, bl1);
    }
  }

  // epilogue: io += bcc + b2  (C frag: col = c31-based, row = reg-based)
  const float b2c0 = b2[wc * 64 + c31];
  const float b2c1 = b2[wc * 64 + 32 + c31];
  #pragma unroll
  for (int rg = 0; rg < 16; ++rg) {
    int rr = (rg & 3) + 8 * (rg >> 2) + 4 * hi;
    size_t row0 = (size_t)(r0 + wr * 64 + rr) * C_;
    size_t row1 = (size_t)(r0 + wr * 64 + 32 + rr) * C_;
    io[row0 + wc * 64 + c31]      += bcc00[rg] + b2c0;
    io[row0 + wc * 64 + 32 + c31] += bcc01[rg] + b2c1;
    io[row1 + wc * 64 + c31]      += bcc10[rg] + b2c0;
    io[row1 + wc * 64 + 32 + c31] += bcc11[rg] + b2c1;
  }
#undef LOADA
}

// ---- structural kernels (fp32, unchanged) ----
__global__ void agg_fine(const float* __restrict__ e, float* __restrict__ agg) {
  int idx = blockIdx.x * 256 + threadIdx.x;
  int n = idx >> 5;
  int c4 = (idx & 31) * 4;
  int i = n >> 7, j = n & 127;
  float4 s = make_float4(0.f, 0.f, 0.f, 0.f);
  if (j >= 1)   add4(s, e + (i*127 + (j-1)) * C_ + c4);
  if (j <= 126) add4(s, e + (16256 + i*127 + j) * C_ + c4);
  if (i >= 1)   add4(s, e + (32512 + (i-1)*128 + j) * C_ + c4);
  if (i <= 126) add4(s, e + (48768 + i*128 + j) * C_ + c4);
  *(float4*)(agg + n * C_ + c4) = s;
}

__global__ void agg_coarse(const float* __restrict__ e1, float* __restrict__ agg1) {
  int idx = blockIdx.x * 256 + threadIdx.x;
  int m = idx >> 5;
  int c4 = (idx & 31) * 4;
  int ci = m >> 5, cj = m & 31;
  float4 s = make_float4(0.f, 0.f, 0.f, 0.f);
  if (ci > 0)  add4(s, e1 + (cprefix(ci-1,cj) + (ci-1>0) + (cj>0) + (cj<31)) * C_ + c4);
  if (cj > 0)  add4(s, e1 + (cprefix(ci,cj-1) + (ci>0) + (cj-1>0)) * C_ + c4);
  if (cj < 31) add4(s, e1 + (cprefix(ci,cj+1) + (ci>0)) * C_ + c4);
  if (ci < 31) add4(s, e1 + (cprefix(ci+1,cj)) * C_ + c4);
  *(float4*)(agg1 + m * C_ + c4) = s;
}

__global__ void pool_x(const float* __restrict__ x, float* __restrict__ x1) {
  int idx = blockIdx.x * 256 + threadIdx.x;
  int m = idx >> 5;
  int c4 = (idx & 31) * 4;
  int ci = m >> 5, cj = m & 31;
  float4 s = make_float4(0.f, 0.f, 0.f, 0.f);
  #pragma unroll
  for (int a = 0; a < 4; ++a)
    #pragma unroll
    for (int b = 0; b < 4; ++b)
      add4(s, x + ((4*ci + a) * 128 + 4*cj + b) * C_ + c4);
  s.x *= 0.0625f; s.y *= 0.0625f; s.z *= 0.0625f; s.w *= 0.0625f;
  *(float4*)(x1 + m * C_ + c4) = s;
}

__global__ void pool_e(const float* __restrict__ e, float* __restrict__ e1) {
  int idx = blockIdx.x * 256 + threadIdx.x;
  int combo = idx >> 5;
  int c4 = (idx & 31) * 4;
  int m = combo >> 2, dir = combo & 3;
  int ci = m >> 5, cj = m & 31;
  int cid, f0, fstep;
  if (dir == 0) { if (ci == 0) return;
    cid = cprefix(ci,cj);
    f0 = 48768 + (4*ci - 1) * 128 + 4*cj; fstep = 1;
  } else if (dir == 1) { if (cj == 0) return;
    cid = cprefix(ci,cj) + (ci>0);
    f0 = 16256 + (4*ci) * 127 + 4*cj - 1; fstep = 127;
  } else if (dir == 2) { if (cj == 31) return;
    cid = cprefix(ci,cj) + (ci>0) + (cj>0);
    f0 = (4*ci) * 127 + 4*cj + 3; fstep = 127;
  } else { if (ci == 31) return;
    cid = cprefix(ci,cj) + (ci>0) + (cj>0) + (cj<31);
    f0 = 32512 + (4*ci + 3) * 128 + 4*cj; fstep = 1;
  }
  float4 s = make_float4(0.f, 0.f, 0.f, 0.f);
  #pragma unroll
  for (int k = 0; k < 4; ++k)
    add4(s, e + (f0 + k * fstep) * C_ + c4);
  *(float4*)(e1 + cid * C_ + c4) = s;
}

__global__ void unpool_x(float* __restrict__ x, const float* __restrict__ x1,
                         const int* __restrict__ perm) {
  int idx = blockIdx.x * 256 + threadIdx.x;
  int n = idx >> 5, c4 = (idx & 31) * 4;
  int m = perm[n];
  float4 v = *(const float4*)(x + n * C_ + c4);
  add4(v, x1 + m * C_ + c4);
  *(float4*)(x + n * C_ + c4) = v;
}

__global__ void unpool_e(float* __restrict__ e, const float* __restrict__ e1,
                         const int* __restrict__ pe) {
  int idx = blockIdx.x * 256 + threadIdx.x;
  int k = idx >> 5, c4 = (idx & 31) * 4;
  int fe = pe[k];
  float4 v = *(const float4*)(e + fe * C_ + c4);
  add4(v, e1 + k * C_ + c4);
  *(float4*)(e + fe * C_ + c4) = v;
}

extern "C" void kernel_launch(void* const* d_in, const int* in_sizes, int n_in,
                              void* d_out, int out_size, void* d_ws, size_t ws_size,
                              hipStream_t stream) {
  const float* in_x  = (const float*)d_in[0];
  const float* in_ea = (const float*)d_in[1];
  const float* We1 = (const float*)d_in[2];
  const float* be1 = (const float*)d_in[3];
  const float* We2 = (const float*)d_in[4];
  const float* be2 = (const float*)d_in[5];
  const float* Wn1 = (const float*)d_in[6];
  const float* bn1 = (const float*)d_in[7];
  const float* Wn2 = (const float*)d_in[8];
  const float* bn2 = (const float*)d_in[9];
  const int* ei   = (const int*)d_in[10];
  const int* perm = (const int*)d_in[11];
  const int* pei  = (const int*)d_in[12];
  const int* pe   = (const int*)d_in[14];

  // outputs live in place
  float* x = (float*)d_out;             // N0 x 128
  float* e = x + (size_t)N0 * C_;       // E0 x 128
  // scratch in d_ws
  float* agg  = (float*)d_ws;           // N0 x 128
  float* x1   = agg + (size_t)N0 * C_;  // NC x 128
  float* e1   = x1 + (size_t)NC_ * C_;  // E1 x 128
  float* agg1 = e1 + (size_t)E1C * C_;  // NC x 128
  short* wsH  = (short*)(agg1 + (size_t)NC_ * C_);
  short* wsL  = wsH + W_TOTAL;

  hipMemcpyAsync(x, in_x, (size_t)N0 * C_ * 4, hipMemcpyDeviceToDevice, stream);
  hipMemcpyAsync(e, in_ea, (size_t)E0 * C_ * 4, hipMemcpyDeviceToDevice, stream);

  prep_weights<<<W_TOTAL / 256, 256, 0, stream>>>(We1, We2, Wn1, Wn2, wsH, wsL);

  const int* srcF = ei;  const int* dstF = ei + E0;
  const int* srcC = pei; const int* dstC = pei + E1C;

  #define WE1_OFF(l) (OFF_WE1 + (l) * 49152)
  #define WE2_OFF(l) (OFF_WE2 + (l) * 16384)
  #define WN1_OFF(l) (OFF_WN1 + (l) * 32768)
  #define WN2_OFF(l) (OFF_WN2 + (l) * 16384)

  for (int l = 0; l < 2; ++l) {
    mlp_mfma<0><<<E0/128, 256, 0, stream>>>(e, x, srcF, dstF,
        wsH + WE1_OFF(l), wsL + WE1_OFF(l), be1 + l*C_,
        wsH + WE2_OFF(l), wsL + WE2_OFF(l), be2 + l*C_);
    agg_fine<<<N0*32/256, 256, 0, stream>>>(e, agg);
    mlp_mfma<1><<<N0/128, 256, 0, stream>>>(x, agg, nullptr, nullptr,
        wsH + WN1_OFF(l), wsL + WN1_OFF(l), bn1 + l*C_,
        wsH + WN2_OFF(l), wsL + WN2_OFF(l), bn2 + l*C_);
  }

  pool_x<<<NC_*32/256, 256, 0, stream>>>(x, x1);
  pool_e<<<NC_*4*32/256, 256, 0, stream>>>(e, e1);

  for (int l = 2; l < 4; ++l) {
    mlp_mfma<0><<<E1C/128, 256, 0, stream>>>(e1, x1, srcC, dstC,
        wsH + WE1_OFF(l), wsL + WE1_OFF(l), be1 + l*C_,
        wsH + WE2_OFF(l), wsL + WE2_OFF(l), be2 + l*C_);
    agg_coarse<<<NC_*32/256, 256, 0, stream>>>(e1, agg1);
    mlp_mfma<1><<<NC_/128, 256, 0, stream>>>(x1, agg1, nullptr, nullptr,
        wsH + WN1_OFF(l), wsL + WN1_OFF(l), bn1 + l*C_,
        wsH + WN2_OFF(l), wsL + WN2_OFF(l), bn2 + l*C_);
  }

  unpool_x<<<N0*32/256, 256, 0, stream>>>(x, x1, perm);
  unpool_e<<<E1C*32/256, 256, 0, stream>>>(e, e1, pe);

  for (int l = 4; l < 6; ++l) {
    mlp_mfma<0><<<E0/128, 256, 0, stream>>>(e, x, srcF, dstF,
        wsH + WE1_OFF(l), wsL + WE1_OFF(l), be1 + l*C_,
        wsH + WE2_OFF(l), wsL + WE2_OFF(l), be2 + l*C_);
    agg_fine<<<N0*32/256, 256, 0, stream>>>(e, agg);
    mlp_mfma<1><<<N0/128, 256, 0, stream>>>(x, agg, nullptr, nullptr,
        wsH + WN1_OFF(l), wsL + WN1_OFF(l), bn1 + l*C_,
        wsH + WN2_OFF(l), wsL + WN2_OFF(l), bn2 + l*C_);
  }
}

// Round 9
// 499.501 us; speedup vs baseline: 1.0984x; 1.0984x over previous
//
#include <hip/hip_runtime.h>

#define C_ 128
#define N0 16384
#define E0 65024
#define NC_ 1024
#define E1C 3968
#define LSTR 40    // W-tile stride in shorts (80B = 5*16B, odd 16B-units -> uniform slots)
#define HSTR 36    // packed-H stride in u32 (144B = 9*16B, odd)

typedef __attribute__((ext_vector_type(8))) short bf16x8;
typedef __attribute__((ext_vector_type(16))) float f32x16;

// weight table offsets (in shorts) inside the ws bf16 region
#define OFF_WE1 0
#define OFF_WE2 294912
#define OFF_WN1 393216
#define OFF_WN2 589824
#define W_TOTAL 688128

__device__ __forceinline__ void bsplit(float a, unsigned short& hi, unsigned short& lo) {
  unsigned ab = __float_as_uint(a);
  unsigned hb = ab & 0xFFFF0000u;          // truncate to bf16
  hi = (unsigned short)(hb >> 16);
  float r = a - __uint_as_float(hb);       // exact residual
  lo = (unsigned short)(__float_as_uint(r) >> 16);
}

__device__ __forceinline__ int cprefix(int ci, int cj) {
  int rows = (ci == 0) ? 0 : (94 + (ci - 1) * 126);
  int v = (ci > 0) + (ci < 31);
  int within = (cj == 0) ? 0 : (2 * cj - 1);
  return rows + within + cj * v;
}

__device__ __forceinline__ void add4(float4& s, const float* p) {
  float4 v = *(const float4*)p;
  s.x += v.x; s.y += v.y; s.z += v.z; s.w += v.w;
}

__device__ __forceinline__ f32x16 zero16() {
  f32x16 z;
  #pragma unroll
  for (int i = 0; i < 16; ++i) z[i] = 0.f;
  return z;
}

// ---- one-time weight transpose + bf16 hi/lo split: [layer][K/32][128 cols][32 k] ----
__global__ void prep_weights(const float* __restrict__ We1, const float* __restrict__ We2,
                             const float* __restrict__ Wn1, const float* __restrict__ Wn2,
                             short* __restrict__ wh, short* __restrict__ wl) {
  int idx = blockIdx.x * 256 + threadIdx.x;   // < 688128
  const float* src; int Kt, off, rem;
  if (idx < 294912)      { src = We1; Kt = 384; off = OFF_WE1; rem = idx; }
  else if (idx < 393216) { src = We2; Kt = 128; off = OFF_WE2; rem = idx - 294912; }
  else if (idx < 589824) { src = Wn1; Kt = 256; off = OFF_WN1; rem = idx - 393216; }
  else                   { src = Wn2; Kt = 128; off = OFF_WN2; rem = idx - 589824; }
  int per_layer = Kt << 7;
  int layer = rem / per_layer;
  int r2 = rem - layer * per_layer;
  int k = r2 >> 7;
  int col = r2 & 127;
  float a = src[layer * per_layer + (k << 7) + col];
  unsigned short hi, lo;
  bsplit(a, hi, lo);
  int dst = off + layer * ((Kt >> 5) << 12) + ((k >> 5) << 12) + (col << 5) + (k & 31);
  wh[dst] = (short)hi;
  wl[dst] = (short)lo;
}

#define BSPLIT8(V0, V1, AH, AL) do { \
    unsigned short h0_,h1_,h2_,h3_,h4_,h5_,h6_,h7_, l0_,l1_,l2_,l3_,l4_,l5_,l6_,l7_; \
    bsplit((V0).x,h0_,l0_); bsplit((V0).y,h1_,l1_); bsplit((V0).z,h2_,l2_); bsplit((V0).w,h3_,l3_); \
    bsplit((V1).x,h4_,l4_); bsplit((V1).y,h5_,l5_); bsplit((V1).z,h6_,l6_); bsplit((V1).w,h7_,l7_); \
    AH = (bf16x8){(short)h0_,(short)h1_,(short)h2_,(short)h3_,(short)h4_,(short)h5_,(short)h6_,(short)h7_}; \
    AL = (bf16x8){(short)l0_,(short)l1_,(short)l2_,(short)l3_,(short)l4_,(short)l5_,(short)l6_,(short)l7_}; \
  } while (0)

#define MFMA3(ACC, AH, AL, BH, BL) do { \
    ACC = __builtin_amdgcn_mfma_f32_32x32x16_bf16(AH, BH, ACC, 0, 0, 0); \
    ACC = __builtin_amdgcn_mfma_f32_32x32x16_bf16(AH, BL, ACC, 0, 0, 0); \
    ACC = __builtin_amdgcn_mfma_f32_32x32x16_bf16(AL, BH, ACC, 0, 0, 0); \
  } while (0)

#define UNPACKH(ROW, S, AH, AL) do { \
    const unsigned* hp_ = &sH[(ROW) * HSTR + (S) * 16 + hi * 8]; \
    uint4 u0_ = *(const uint4*)hp_; uint4 u1_ = *(const uint4*)(hp_ + 4); \
    AH = (bf16x8){(short)(u0_.x & 0xFFFFu), (short)(u0_.y & 0xFFFFu), (short)(u0_.z & 0xFFFFu), (short)(u0_.w & 0xFFFFu), \
                  (short)(u1_.x & 0xFFFFu), (short)(u1_.y & 0xFFFFu), (short)(u1_.z & 0xFFFFu), (short)(u1_.w & 0xFFFFu)}; \
    AL = (bf16x8){(short)(u0_.x >> 16), (short)(u0_.y >> 16), (short)(u0_.z >> 16), (short)(u0_.w >> 16), \
                  (short)(u1_.x >> 16), (short)(u1_.y >> 16), (short)(u1_.z >> 16), (short)(u1_.w >> 16)}; \
  } while (0)

// T14 async-STAGE split: LOADW issues global loads into regs (early); WRITEW
// commits them to LDS inside the barrier pair (late). The load latency hides
// under the previous chunk's MFMA phase instead of being serially exposed.
#define LOADW(WH, WL, KC) do { \
    const short* sh_ = (WH) + ((KC) << 12); \
    const short* sl_ = (WL) + ((KC) << 12); \
    wv0 = *(const uint4*)(sh_ + tid * 8); \
    wv1 = *(const uint4*)(sh_ + (tid + 256) * 8); \
    wv2 = *(const uint4*)(sl_ + tid * 8); \
    wv3 = *(const uint4*)(sl_ + (tid + 256) * 8); \
  } while (0)

#define WRITEW() do { \
    *(uint4*)&sWh[(tid >> 2) * LSTR + (tid & 3) * 8] = wv0; \
    *(uint4*)&sWh[((tid + 256) >> 2) * LSTR + (tid & 3) * 8] = wv1; \
    *(uint4*)&sWl[(tid >> 2) * LSTR + (tid & 3) * 8] = wv2; \
    *(uint4*)&sWl[((tid + 256) >> 2) * LSTR + (tid & 3) * 8] = wv3; \
  } while (0)

// MODE 0: edge MLP, K1=384, A = [e_row | x[src] | x[dst]]
// MODE 1: node MLP, K1=256, A = [x_row | agg_row]
// io = io + relu(A@W1 + b1)@W2 + b2. 128x128 block tile, 4 waves (2x2), 32x32 MFMA,
// bf16 hi/lo split (3 mfma/product). A frags read direct from global (lane=row).
template<int MODE>
__global__ __launch_bounds__(256, 2) void mlp_mfma(
    float* __restrict__ io, const float* __restrict__ xin,
    const int* __restrict__ srcI, const int* __restrict__ dstI,
    const short* __restrict__ W1h, const short* __restrict__ W1l,
    const float* __restrict__ b1,
    const short* __restrict__ W2h, const short* __restrict__ W2l,
    const float* __restrict__ b2)
{
  __shared__ alignas(16) short sWh[128 * LSTR], sWl[128 * LSTR];   // 20.0 KiB
  __shared__ alignas(16) unsigned sH[128 * HSTR];                  // 18.0 KiB (packed hi|lo<<16)

  const int tid = threadIdx.x;
  const int w   = tid >> 6;
  const int wr  = w >> 1;         // row half: rows [wr*64, +64)
  const int wc  = w & 1;          // col half: cols [wc*64, +64)
  const int l   = tid & 63;
  const int c31 = l & 31;
  const int hi  = l >> 5;         // k-subgroup (8 wide)
  const int r0  = blockIdx.x * 128;

  // per-lane A row pointers (lane c31 = fragment row; rt in {0,1})
  const int ar0 = wr * 64 + c31;
  const int ar1 = ar0 + 32;
  const float* pio0 = io + (size_t)(r0 + ar0) * C_;
  const float* pio1 = io + (size_t)(r0 + ar1) * C_;
  const float *px0, *px1, *pd0, *pd1;
  if (MODE == 0) {
    px0 = xin + (size_t)srcI[r0 + ar0] * C_;
    px1 = xin + (size_t)srcI[r0 + ar1] * C_;
    pd0 = xin + (size_t)dstI[r0 + ar0] * C_;
    pd1 = xin + (size_t)dstI[r0 + ar1] * C_;
  } else {
    px0 = xin + (size_t)(r0 + ar0) * C_;
    px1 = xin + (size_t)(r0 + ar1) * C_;
    pd0 = px0; pd1 = px1;  // unused
  }

  float4 pa00, pa01, pa02, pa03, pa10, pa11, pa12, pa13;
  uint4 wv0, wv1, wv2, wv3;      // in-flight W chunk (T14 reg staging)
#define LOADA(KC) do { \
    int rg_ = (KC) >> 2; int cb_ = ((KC) & 3) * 32 + hi * 8; \
    const float* q0_; const float* q1_; \
    if (MODE == 0) { q0_ = (rg_ == 0) ? pio0 : (rg_ == 1) ? px0 : pd0; \
                     q1_ = (rg_ == 0) ? pio1 : (rg_ == 1) ? px1 : pd1; } \
    else           { q0_ = (rg_ == 0) ? pio0 : px0; \
                     q1_ = (rg_ == 0) ? pio1 : px1; } \
    pa00 = *(const float4*)(q0_ + cb_);      pa01 = *(const float4*)(q0_ + cb_ + 4); \
    pa02 = *(const float4*)(q0_ + cb_ + 16); pa03 = *(const float4*)(q0_ + cb_ + 20); \
    pa10 = *(const float4*)(q1_ + cb_);      pa11 = *(const float4*)(q1_ + cb_ + 4); \
    pa12 = *(const float4*)(q1_ + cb_ + 16); pa13 = *(const float4*)(q1_ + cb_ + 20); \
  } while (0)

  f32x16 acc00 = zero16(), acc01 = zero16(), acc10 = zero16(), acc11 = zero16();

  // ---------------- GEMM1 ----------------
  const int NK1 = (MODE == 0) ? 12 : 8;
  LOADA(0);
  LOADW(W1h, W1l, 0);
  for (int kc = 0; kc < NK1; ++kc) {
    bf16x8 ah0s0, al0s0, ah0s1, al0s1, ah1s0, al1s0, ah1s1, al1s1;
    BSPLIT8(pa00, pa01, ah0s0, al0s0);
    BSPLIT8(pa02, pa03, ah0s1, al0s1);
    BSPLIT8(pa10, pa11, ah1s0, al1s0);
    BSPLIT8(pa12, pa13, ah1s1, al1s1);
    if (kc + 1 < NK1) LOADA(kc + 1);
    __syncthreads();                       // all waves done reading sW chunk kc-1
    WRITEW();                              // commit prefetched W chunk kc
    __syncthreads();                       // sW chunk kc ready
    if (kc + 1 < NK1) LOADW(W1h, W1l, kc + 1);   // issue next-chunk loads,
    else              LOADW(W2h, W2l, 0);        // hide under MFMA below
    #pragma unroll
    for (int s = 0; s < 2; ++s) {
      const int wb = s * 16 + hi * 8;
      bf16x8 bh0 = *(const bf16x8*)&sWh[(wc * 64 + c31) * LSTR + wb];
      bf16x8 bl0 = *(const bf16x8*)&sWl[(wc * 64 + c31) * LSTR + wb];
      bf16x8 bh1 = *(const bf16x8*)&sWh[(wc * 64 + 32 + c31) * LSTR + wb];
      bf16x8 bl1 = *(const bf16x8*)&sWl[(wc * 64 + 32 + c31) * LSTR + wb];
      if (s == 0) {
        MFMA3(acc00, ah0s0, al0s0, bh0, bl0);
        MFMA3(acc01, ah0s0, al0s0, bh1, bl1);
        MFMA3(acc10, ah1s0, al1s0, bh0, bl0);
        MFMA3(acc11, ah1s0, al1s0, bh1, bl1);
      } else {
        MFMA3(acc00, ah0s1, al0s1, bh0, bl0);
        MFMA3(acc01, ah0s1, al0s1, bh1, bl1);
        MFMA3(acc10, ah1s1, al1s1, bh0, bl0);
        MFMA3(acc11, ah1s1, al1s1, bh1, bl1);
      }
    }
  }

  // ---------------- GEMM2 (H @ W2), H chunked through sH ----------------
  f32x16 bcc00 = zero16(), bcc01 = zero16(), bcc10 = zero16(), bcc11 = zero16();
  #pragma unroll
  for (int kc = 0; kc < 4; ++kc) {
    __syncthreads();                       // prior sW/sH reads done
    if (wc == (kc >> 1)) {                 // this wave owns H cols [kc*32, +32)
      const float bb = b1[(kc >> 1) * 64 + (kc & 1) * 32 + c31];
      #pragma unroll
      for (int rg = 0; rg < 16; ++rg) {
        int rr = (rg & 3) + 8 * (rg >> 2) + 4 * hi;
        float h0 = fmaxf(((kc & 1) ? acc01[rg] : acc00[rg]) + bb, 0.f);
        float h1 = fmaxf(((kc & 1) ? acc11[rg] : acc10[rg]) + bb, 0.f);
        unsigned short hh, hl;
        bsplit(h0, hh, hl);
        sH[(wr * 64 + rr) * HSTR + c31] = (unsigned)hh | ((unsigned)hl << 16);
        bsplit(h1, hh, hl);
        sH[(wr * 64 + 32 + rr) * HSTR + c31] = (unsigned)hh | ((unsigned)hl << 16);
      }
    }
    WRITEW();                              // commit prefetched W2 chunk kc
    __syncthreads();                       // sH chunk + sW chunk ready
    if (kc < 3) LOADW(W2h, W2l, kc + 1);   // issue next W2 loads under MFMA
    #pragma unroll
    for (int s = 0; s < 2; ++s) {
      bf16x8 ah0, al0, ah1, al1;
      UNPACKH(wr * 64 + c31, s, ah0, al0);
      UNPACKH(wr * 64 + 32 + c31, s, ah1, al1);
      const int wb = s * 16 + hi * 8;
      bf16x8 bh0 = *(const bf16x8*)&sWh[(wc * 64 + c31) * LSTR + wb];
      bf16x8 bl0 = *(const bf16x8*)&sWl[(wc * 64 + c31) * LSTR + wb];
      bf16x8 bh1 = *(const bf16x8*)&sWh[(wc * 64 + 32 + c31) * LSTR + wb];
      bf16x8 bl1 = *(const bf16x8*)&sWl[(wc * 64 + 32 + c31) * LSTR + wb];
      MFMA3(bcc00, ah0, al0, bh0, bl0);
      MFMA3(bcc01, ah0, al0, bh1, bl1);
      MFMA3(bcc10, ah1, al1, bh0, bl0);
      MFMA3(bcc11, ah1, al1, bh1, bl1);
    }
  }

  // epilogue: io += bcc + b2  (C frag: col = c31-based, row = reg-based)
  const float b2c0 = b2[wc * 64 + c31];
  const float b2c1 = b2[wc * 64 + 32 + c31];
  #pragma unroll
  for (int rg = 0; rg < 16; ++rg) {
    int rr = (rg & 3) + 8 * (rg >> 2) + 4 * hi;
    size_t row0 = (size_t)(r0 + wr * 64 + rr) * C_;
    size_t row1 = (size_t)(r0 + wr * 64 + 32 + rr) * C_;
    io[row0 + wc * 64 + c31]      += bcc00[rg] + b2c0;
    io[row0 + wc * 64 + 32 + c31] += bcc01[rg] + b2c1;
    io[row1 + wc * 64 + c31]      += bcc10[rg] + b2c0;
    io[row1 + wc * 64 + 32 + c31] += bcc11[rg] + b2c1;
  }
#undef LOADA
}

// ---- structural kernels (fp32, unchanged) ----
__global__ void agg_fine(const float* __restrict__ e, float* __restrict__ agg) {
  int idx = blockIdx.x * 256 + threadIdx.x;
  int n = idx >> 5;
  int c4 = (idx & 31) * 4;
  int i = n >> 7, j = n & 127;
  float4 s = make_float4(0.f, 0.f, 0.f, 0.f);
  if (j >= 1)   add4(s, e + (i*127 + (j-1)) * C_ + c4);
  if (j <= 126) add4(s, e + (16256 + i*127 + j) * C_ + c4);
  if (i >= 1)   add4(s, e + (32512 + (i-1)*128 + j) * C_ + c4);
  if (i <= 126) add4(s, e + (48768 + i*128 + j) * C_ + c4);
  *(float4*)(agg + n * C_ + c4) = s;
}

__global__ void agg_coarse(const float* __restrict__ e1, float* __restrict__ agg1) {
  int idx = blockIdx.x * 256 + threadIdx.x;
  int m = idx >> 5;
  int c4 = (idx & 31) * 4;
  int ci = m >> 5, cj = m & 31;
  float4 s = make_float4(0.f, 0.f, 0.f, 0.f);
  if (ci > 0)  add4(s, e1 + (cprefix(ci-1,cj) + (ci-1>0) + (cj>0) + (cj<31)) * C_ + c4);
  if (cj > 0)  add4(s, e1 + (cprefix(ci,cj-1) + (ci>0) + (cj-1>0)) * C_ + c4);
  if (cj < 31) add4(s, e1 + (cprefix(ci,cj+1) + (ci>0)) * C_ + c4);
  if (ci < 31) add4(s, e1 + (cprefix(ci+1,cj)) * C_ + c4);
  *(float4*)(agg1 + m * C_ + c4) = s;
}

__global__ void pool_x(const float* __restrict__ x, float* __restrict__ x1) {
  int idx = blockIdx.x * 256 + threadIdx.x;
  int m = idx >> 5;
  int c4 = (idx & 31) * 4;
  int ci = m >> 5, cj = m & 31;
  float4 s = make_float4(0.f, 0.f, 0.f, 0.f);
  #pragma unroll
  for (int a = 0; a < 4; ++a)
    #pragma unroll
    for (int b = 0; b < 4; ++b)
      add4(s, x + ((4*ci + a) * 128 + 4*cj + b) * C_ + c4);
  s.x *= 0.0625f; s.y *= 0.0625f; s.z *= 0.0625f; s.w *= 0.0625f;
  *(float4*)(x1 + m * C_ + c4) = s;
}

__global__ void pool_e(const float* __restrict__ e, float* __restrict__ e1) {
  int idx = blockIdx.x * 256 + threadIdx.x;
  int combo = idx >> 5;
  int c4 = (idx & 31) * 4;
  int m = combo >> 2, dir = combo & 3;
  int ci = m >> 5, cj = m & 31;
  int cid, f0, fstep;
  if (dir == 0) { if (ci == 0) return;
    cid = cprefix(ci,cj);
    f0 = 48768 + (4*ci - 1) * 128 + 4*cj; fstep = 1;
  } else if (dir == 1) { if (cj == 0) return;
    cid = cprefix(ci,cj) + (ci>0);
    f0 = 16256 + (4*ci) * 127 + 4*cj - 1; fstep = 127;
  } else if (dir == 2) { if (cj == 31) return;
    cid = cprefix(ci,cj) + (ci>0) + (cj>0);
    f0 = (4*ci) * 127 + 4*cj + 3; fstep = 127;
  } else { if (ci == 31) return;
    cid = cprefix(ci,cj) + (ci>0) + (cj>0) + (cj<31);
    f0 = 32512 + (4*ci + 3) * 128 + 4*cj; fstep = 1;
  }
  float4 s = make_float4(0.f, 0.f, 0.f, 0.f);
  #pragma unroll
  for (int k = 0; k < 4; ++k)
    add4(s, e + (f0 + k * fstep) * C_ + c4);
  *(float4*)(e1 + cid * C_ + c4) = s;
}

__global__ void unpool_x(float* __restrict__ x, const float* __restrict__ x1,
                         const int* __restrict__ perm) {
  int idx = blockIdx.x * 256 + threadIdx.x;
  int n = idx >> 5, c4 = (idx & 31) * 4;
  int m = perm[n];
  float4 v = *(const float4*)(x + n * C_ + c4);
  add4(v, x1 + m * C_ + c4);
  *(float4*)(x + n * C_ + c4) = v;
}

__global__ void unpool_e(float* __restrict__ e, const float* __restrict__ e1,
                         const int* __restrict__ pe) {
  int idx = blockIdx.x * 256 + threadIdx.x;
  int k = idx >> 5, c4 = (idx & 31) * 4;
  int fe = pe[k];
  float4 v = *(const float4*)(e + fe * C_ + c4);
  add4(v, e1 + k * C_ + c4);
  *(float4*)(e + fe * C_ + c4) = v;
}

extern "C" void kernel_launch(void* const* d_in, const int* in_sizes, int n_in,
                              void* d_out, int out_size, void* d_ws, size_t ws_size,
                              hipStream_t stream) {
  const float* in_x  = (const float*)d_in[0];
  const float* in_ea = (const float*)d_in[1];
  const float* We1 = (const float*)d_in[2];
  const float* be1 = (const float*)d_in[3];
  const float* We2 = (const float*)d_in[4];
  const float* be2 = (const float*)d_in[5];
  const float* Wn1 = (const float*)d_in[6];
  const float* bn1 = (const float*)d_in[7];
  const float* Wn2 = (const float*)d_in[8];
  const float* bn2 = (const float*)d_in[9];
  const int* ei   = (const int*)d_in[10];
  const int* perm = (const int*)d_in[11];
  const int* pei  = (const int*)d_in[12];
  const int* pe   = (const int*)d_in[14];

  // outputs live in place
  float* x = (float*)d_out;             // N0 x 128
  float* e = x + (size_t)N0 * C_;       // E0 x 128
  // scratch in d_ws
  float* agg  = (float*)d_ws;           // N0 x 128
  float* x1   = agg + (size_t)N0 * C_;  // NC x 128
  float* e1   = x1 + (size_t)NC_ * C_;  // E1 x 128
  float* agg1 = e1 + (size_t)E1C * C_;  // NC x 128
  short* wsH  = (short*)(agg1 + (size_t)NC_ * C_);
  short* wsL  = wsH + W_TOTAL;

  hipMemcpyAsync(x, in_x, (size_t)N0 * C_ * 4, hipMemcpyDeviceToDevice, stream);
  hipMemcpyAsync(e, in_ea, (size_t)E0 * C_ * 4, hipMemcpyDeviceToDevice, stream);

  prep_weights<<<W_TOTAL / 256, 256, 0, stream>>>(We1, We2, Wn1, Wn2, wsH, wsL);

  const int* srcF = ei;  const int* dstF = ei + E0;
  const int* srcC = pei; const int* dstC = pei + E1C;

  #define WE1_OFF(l) (OFF_WE1 + (l) * 49152)
  #define WE2_OFF(l) (OFF_WE2 + (l) * 16384)
  #define WN1_OFF(l) (OFF_WN1 + (l) * 32768)
  #define WN2_OFF(l) (OFF_WN2 + (l) * 16384)

  for (int l = 0; l < 2; ++l) {
    mlp_mfma<0><<<E0/128, 256, 0, stream>>>(e, x, srcF, dstF,
        wsH + WE1_OFF(l), wsL + WE1_OFF(l), be1 + l*C_,
        wsH + WE2_OFF(l), wsL + WE2_OFF(l), be2 + l*C_);
    agg_fine<<<N0*32/256, 256, 0, stream>>>(e, agg);
    mlp_mfma<1><<<N0/128, 256, 0, stream>>>(x, agg, nullptr, nullptr,
        wsH + WN1_OFF(l), wsL + WN1_OFF(l), bn1 + l*C_,
        wsH + WN2_OFF(l), wsL + WN2_OFF(l), bn2 + l*C_);
  }

  pool_x<<<NC_*32/256, 256, 0, stream>>>(x, x1);
  pool_e<<<NC_*4*32/256, 256, 0, stream>>>(e, e1);

  for (int l = 2; l < 4; ++l) {
    mlp_mfma<0><<<E1C/128, 256, 0, stream>>>(e1, x1, srcC, dstC,
        wsH + WE1_OFF(l), wsL + WE1_OFF(l), be1 + l*C_,
        wsH + WE2_OFF(l), wsL + WE2_OFF(l), be2 + l*C_);
    agg_coarse<<<NC_*32/256, 256, 0, stream>>>(e1, agg1);
    mlp_mfma<1><<<NC_/128, 256, 0, stream>>>(x1, agg1, nullptr, nullptr,
        wsH + WN1_OFF(l), wsL + WN1_OFF(l), bn1 + l*C_,
        wsH + WN2_OFF(l), wsL + WN2_OFF(l), bn2 + l*C_);
  }

  unpool_x<<<N0*32/256, 256, 0, stream>>>(x, x1, perm);
  unpool_e<<<E1C*32/256, 256, 0, stream>>>(e, e1, pe);

  for (int l = 4; l < 6; ++l) {
    mlp_mfma<0><<<E0/128, 256, 0, stream>>>(e, x, srcF, dstF,
        wsH + WE1_OFF(l), wsL + WE1_OFF(l), be1 + l*C_,
        wsH + WE2_OFF(l), wsL + WE2_OFF(l), be2 + l*C_);
    agg_fine<<<N0*32/256, 256, 0, stream>>>(e, agg);
    mlp_mfma<1><<<N0/128, 256, 0, stream>>>(x, agg, nullptr, nullptr,
        wsH + WN1_OFF(l), wsL + WN1_OFF(l), bn1 + l*C_,
        wsH + WN2_OFF(l), wsL + WN2_OFF(l), bn2 + l*C_);
  }
}

// Round 10
// 498.563 us; speedup vs baseline: 1.1005x; 1.0019x over previous
//
#include <hip/hip_runtime.h>

#define C_ 128
#define N0 16384
#define E0 65024
#define NC_ 1024
#define E1C 3968
#define HSTR 36    // packed-H stride in u32 (144B = 9*16B, odd 16B-units -> uniform slots)

typedef __attribute__((ext_vector_type(8))) short bf16x8;
typedef __attribute__((ext_vector_type(16))) float f32x16;

// weight table offsets (in shorts) inside the ws bf16 region
#define OFF_WE1 0
#define OFF_WE2 294912
#define OFF_WN1 393216
#define OFF_WN2 589824
#define W_TOTAL 688128

__device__ __forceinline__ void bsplit(float a, unsigned short& hi, unsigned short& lo) {
  unsigned ab = __float_as_uint(a);
  unsigned hb = ab & 0xFFFF0000u;          // truncate to bf16
  hi = (unsigned short)(hb >> 16);
  float r = a - __uint_as_float(hb);       // exact residual
  lo = (unsigned short)(__float_as_uint(r) >> 16);
}

__device__ __forceinline__ int cprefix(int ci, int cj) {
  int rows = (ci == 0) ? 0 : (94 + (ci - 1) * 126);
  int v = (ci > 0) + (ci < 31);
  int within = (cj == 0) ? 0 : (2 * cj - 1);
  return rows + within + cj * v;
}

__device__ __forceinline__ void add4(float4& s, const float* p) {
  float4 v = *(const float4*)p;
  s.x += v.x; s.y += v.y; s.z += v.z; s.w += v.w;
}

__device__ __forceinline__ f32x16 zero16() {
  f32x16 z;
  #pragma unroll
  for (int i = 0; i < 16; ++i) z[i] = 0.f;
  return z;
}

// ---- one-time weight transpose + bf16 hi/lo split: [layer][K/32][128 cols][32 k] ----
__global__ void prep_weights(const float* __restrict__ We1, const float* __restrict__ We2,
                             const float* __restrict__ Wn1, const float* __restrict__ Wn2,
                             short* __restrict__ wh, short* __restrict__ wl) {
  int idx = blockIdx.x * 256 + threadIdx.x;   // < 688128
  const float* src; int Kt, off, rem;
  if (idx < 294912)      { src = We1; Kt = 384; off = OFF_WE1; rem = idx; }
  else if (idx < 393216) { src = We2; Kt = 128; off = OFF_WE2; rem = idx - 294912; }
  else if (idx < 589824) { src = Wn1; Kt = 256; off = OFF_WN1; rem = idx - 393216; }
  else                   { src = Wn2; Kt = 128; off = OFF_WN2; rem = idx - 589824; }
  int per_layer = Kt << 7;
  int layer = rem / per_layer;
  int r2 = rem - layer * per_layer;
  int k = r2 >> 7;
  int col = r2 & 127;
  float a = src[layer * per_layer + (k << 7) + col];
  unsigned short hi, lo;
  bsplit(a, hi, lo);
  int dst = off + layer * ((Kt >> 5) << 12) + ((k >> 5) << 12) + (col << 5) + (k & 31);
  wh[dst] = (short)hi;
  wl[dst] = (short)lo;
}

#define BSPLIT8(V0, V1, AH, AL) do { \
    unsigned short h0_,h1_,h2_,h3_,h4_,h5_,h6_,h7_, l0_,l1_,l2_,l3_,l4_,l5_,l6_,l7_; \
    bsplit((V0).x,h0_,l0_); bsplit((V0).y,h1_,l1_); bsplit((V0).z,h2_,l2_); bsplit((V0).w,h3_,l3_); \
    bsplit((V1).x,h4_,l4_); bsplit((V1).y,h5_,l5_); bsplit((V1).z,h6_,l6_); bsplit((V1).w,h7_,l7_); \
    AH = (bf16x8){(short)h0_,(short)h1_,(short)h2_,(short)h3_,(short)h4_,(short)h5_,(short)h6_,(short)h7_}; \
    AL = (bf16x8){(short)l0_,(short)l1_,(short)l2_,(short)l3_,(short)l4_,(short)l5_,(short)l6_,(short)l7_}; \
  } while (0)

#define MFMA3(ACC, AH, AL, BH, BL) do { \
    ACC = __builtin_amdgcn_mfma_f32_32x32x16_bf16(AH, BH, ACC, 0, 0, 0); \
    ACC = __builtin_amdgcn_mfma_f32_32x32x16_bf16(AH, BL, ACC, 0, 0, 0); \
    ACC = __builtin_amdgcn_mfma_f32_32x32x16_bf16(AL, BH, ACC, 0, 0, 0); \
  } while (0)

#define UNPACKH(ROW, S, AH, AL) do { \
    const unsigned* hp_ = &sH[(ROW) * HSTR + (S) * 16 + hi * 8]; \
    uint4 u0_ = *(const uint4*)hp_; uint4 u1_ = *(const uint4*)(hp_ + 4); \
    AH = (bf16x8){(short)(u0_.x & 0xFFFFu), (short)(u0_.y & 0xFFFFu), (short)(u0_.z & 0xFFFFu), (short)(u0_.w & 0xFFFFu), \
                  (short)(u1_.x & 0xFFFFu), (short)(u1_.y & 0xFFFFu), (short)(u1_.z & 0xFFFFu), (short)(u1_.w & 0xFFFFu)}; \
    AL = (bf16x8){(short)(u0_.x >> 16), (short)(u0_.y >> 16), (short)(u0_.z >> 16), (short)(u0_.w >> 16), \
                  (short)(u1_.x >> 16), (short)(u1_.y >> 16), (short)(u1_.z >> 16), (short)(u1_.w >> 16)}; \
  } while (0)

// MODE 0: edge MLP, K1=384, A = [e_row | x[src] | x[dst]]
// MODE 1: node MLP, K1=256, A = [x_row | agg_row]
// io = io + relu(A@W1 + b1)@W2 + b2.
// RB = block row-tile (128: 2x2 waves of 64x64; 32: 1x4 waves of 32x32).
// A frags AND W frags read direct from global (W tables are pre-transposed to
// fragment order and L2-resident; staging them in LDS was pure overhead -> the
// whole GEMM1 is barrier-free). Only the H exchange (GEMM2) uses LDS.
template<int MODE, int RB, int MINW>
__global__ __launch_bounds__(256, MINW) void mlp_mfma(
    float* __restrict__ io, const float* __restrict__ xin,
    const int* __restrict__ srcI, const int* __restrict__ dstI,
    const short* __restrict__ W1h, const short* __restrict__ W1l,
    const float* __restrict__ b1,
    const short* __restrict__ W2h, const short* __restrict__ W2l,
    const float* __restrict__ b2)
{
  constexpr int NW_C = (RB == 128) ? 2 : 4;
  constexpr int CW   = 128 / NW_C;          // wave col width: 64 or 32
  constexpr int NCS  = CW / 32;             // col-sets per wave: 2 or 1
  constexpr int NRS  = (RB >= 64) ? 2 : 1;  // row-sets per wave

  __shared__ alignas(16) unsigned sH[RB * HSTR];   // packed H (hi | lo<<16)

  const int tid = threadIdx.x;
  const int w   = tid >> 6;
  const int wr  = (RB == 128) ? (w >> 1) : 0;
  const int wc  = (RB == 128) ? (w & 1) : w;
  const int l   = tid & 63;
  const int c31 = l & 31;
  const int hi  = l >> 5;
  const int r0  = blockIdx.x * RB;

  const float* pio[NRS]; const float* px[NRS]; const float* pd[NRS];
  #pragma unroll
  for (int rs = 0; rs < NRS; ++rs) {
    int ar = wr * 64 + rs * 32 + c31;
    pio[rs] = io + (size_t)(r0 + ar) * C_;
    if (MODE == 0) {
      px[rs] = xin + (size_t)srcI[r0 + ar] * C_;
      pd[rs] = xin + (size_t)dstI[r0 + ar] * C_;
    } else {
      px[rs] = xin + (size_t)(r0 + ar) * C_;
      pd[rs] = px[rs];
    }
  }

  float4 pa[NRS][4];
  auto LOADA = [&](int kc) {
    int rg = kc >> 2, cb = (kc & 3) * 32 + hi * 8;
    #pragma unroll
    for (int rs = 0; rs < NRS; ++rs) {
      const float* q = (MODE == 0)
        ? ((rg == 0) ? pio[rs] : (rg == 1) ? px[rs] : pd[rs])
        : ((rg == 0) ? pio[rs] : px[rs]);
      pa[rs][0] = *(const float4*)(q + cb);
      pa[rs][1] = *(const float4*)(q + cb + 4);
      pa[rs][2] = *(const float4*)(q + cb + 16);
      pa[rs][3] = *(const float4*)(q + cb + 20);
    }
  };

  f32x16 acc[NRS][NCS];
  #pragma unroll
  for (int rs = 0; rs < NRS; ++rs)
    #pragma unroll
    for (int cs = 0; cs < NCS; ++cs) acc[rs][cs] = zero16();

  // ---------------- GEMM1 (barrier-free) ----------------
  const int NK1 = (MODE == 0) ? 12 : 8;
  LOADA(0);
  for (int kc = 0; kc < NK1; ++kc) {
    // W frags direct from global (L2-hot), issued first
    bf16x8 bh[NCS][2], bl[NCS][2];
    {
      const short* bhp = W1h + (kc << 12);
      const short* blp = W1l + (kc << 12);
      #pragma unroll
      for (int cs = 0; cs < NCS; ++cs)
        #pragma unroll
        for (int s = 0; s < 2; ++s) {
          int off = (wc * CW + cs * 32 + c31) * 32 + s * 16 + hi * 8;
          bh[cs][s] = *(const bf16x8*)(bhp + off);
          bl[cs][s] = *(const bf16x8*)(blp + off);
        }
    }
    // bsplit current A (VALU work hides the W load latency)
    bf16x8 ah[NRS][2], al[NRS][2];
    #pragma unroll
    for (int rs = 0; rs < NRS; ++rs) {
      BSPLIT8(pa[rs][0], pa[rs][1], ah[rs][0], al[rs][0]);
      BSPLIT8(pa[rs][2], pa[rs][3], ah[rs][1], al[rs][1]);
    }
    if (kc + 1 < NK1) LOADA(kc + 1);     // next A chunk in flight under MFMA
    #pragma unroll
    for (int s = 0; s < 2; ++s)
      #pragma unroll
      for (int cs = 0; cs < NCS; ++cs)
        #pragma unroll
        for (int rs = 0; rs < NRS; ++rs)
          MFMA3(acc[rs][cs], ah[rs][s], al[rs][s], bh[cs][s], bl[cs][s]);
  }

  // ---------------- GEMM2 (H @ W2), H exchanged through sH ----------------
  f32x16 bcc[NRS][NCS];
  #pragma unroll
  for (int rs = 0; rs < NRS; ++rs)
    #pragma unroll
    for (int cs = 0; cs < NCS; ++cs) bcc[rs][cs] = zero16();

  #pragma unroll
  for (int kc = 0; kc < 4; ++kc) {
    __syncthreads();                       // prior sH reads done
    constexpr int DIV = (RB == 128) ? 2 : 1;
    const int wc_o = (RB == 128) ? (kc >> 1) : kc;
    const int cs_o = (RB == 128) ? (kc & 1) : 0;
    if (wc == wc_o) {                      // this wave owns H cols [kc*32,+32)
      const float bb = b1[kc * 32 + c31];
      #pragma unroll
      for (int rs = 0; rs < NRS; ++rs)
        #pragma unroll
        for (int rg = 0; rg < 16; ++rg) {
          int rr = (rg & 3) + 8 * (rg >> 2) + 4 * hi;
          float h = fmaxf(acc[rs][cs_o][rg] + bb, 0.f);
          unsigned short hh, hl;
          bsplit(h, hh, hl);
          sH[(wr * 64 + rs * 32 + rr) * HSTR + c31] = (unsigned)hh | ((unsigned)hl << 16);
        }
    }
    __syncthreads();                       // sH chunk ready
    bf16x8 bh[NCS][2], bl[NCS][2];
    {
      const short* bhp = W2h + (kc << 12);
      const short* blp = W2l + (kc << 12);
      #pragma unroll
      for (int cs = 0; cs < NCS; ++cs)
        #pragma unroll
        for (int s = 0; s < 2; ++s) {
          int off = (wc * CW + cs * 32 + c31) * 32 + s * 16 + hi * 8;
          bh[cs][s] = *(const bf16x8*)(bhp + off);
          bl[cs][s] = *(const bf16x8*)(blp + off);
        }
    }
    bf16x8 ah[NRS][2], al[NRS][2];
    #pragma unroll
    for (int rs = 0; rs < NRS; ++rs)
      #pragma unroll
      for (int s = 0; s < 2; ++s)
        UNPACKH(wr * 64 + rs * 32 + c31, s, ah[rs][s], al[rs][s]);
    #pragma unroll
    for (int s = 0; s < 2; ++s)
      #pragma unroll
      for (int cs = 0; cs < NCS; ++cs)
        #pragma unroll
        for (int rs = 0; rs < NRS; ++rs)
          MFMA3(bcc[rs][cs], ah[rs][s], al[rs][s], bh[cs][s], bl[cs][s]);
  }

  // epilogue: io += bcc + b2
  #pragma unroll
  for (int cs = 0; cs < NCS; ++cs) {
    const float b2v = b2[wc * CW + cs * 32 + c31];
    #pragma unroll
    for (int rs = 0; rs < NRS; ++rs)
      #pragma unroll
      for (int rg = 0; rg < 16; ++rg) {
        int rr = (rg & 3) + 8 * (rg >> 2) + 4 * hi;
        size_t row = (size_t)(r0 + wr * 64 + rs * 32 + rr) * C_;
        io[row + wc * CW + cs * 32 + c31] += bcc[rs][cs][rg] + b2v;
      }
  }
}

// ---- structural kernels (fp32, unchanged) ----
__global__ void agg_fine(const float* __restrict__ e, float* __restrict__ agg) {
  int idx = blockIdx.x * 256 + threadIdx.x;
  int n = idx >> 5;
  int c4 = (idx & 31) * 4;
  int i = n >> 7, j = n & 127;
  float4 s = make_float4(0.f, 0.f, 0.f, 0.f);
  if (j >= 1)   add4(s, e + (i*127 + (j-1)) * C_ + c4);
  if (j <= 126) add4(s, e + (16256 + i*127 + j) * C_ + c4);
  if (i >= 1)   add4(s, e + (32512 + (i-1)*128 + j) * C_ + c4);
  if (i <= 126) add4(s, e + (48768 + i*128 + j) * C_ + c4);
  *(float4*)(agg + n * C_ + c4) = s;
}

__global__ void agg_coarse(const float* __restrict__ e1, float* __restrict__ agg1) {
  int idx = blockIdx.x * 256 + threadIdx.x;
  int m = idx >> 5;
  int c4 = (idx & 31) * 4;
  int ci = m >> 5, cj = m & 31;
  float4 s = make_float4(0.f, 0.f, 0.f, 0.f);
  if (ci > 0)  add4(s, e1 + (cprefix(ci-1,cj) + (ci-1>0) + (cj>0) + (cj<31)) * C_ + c4);
  if (cj > 0)  add4(s, e1 + (cprefix(ci,cj-1) + (ci>0) + (cj-1>0)) * C_ + c4);
  if (cj < 31) add4(s, e1 + (cprefix(ci,cj+1) + (ci>0)) * C_ + c4);
  if (ci < 31) add4(s, e1 + (cprefix(ci+1,cj)) * C_ + c4);
  *(float4*)(agg1 + m * C_ + c4) = s;
}

__global__ void pool_x(const float* __restrict__ x, float* __restrict__ x1) {
  int idx = blockIdx.x * 256 + threadIdx.x;
  int m = idx >> 5;
  int c4 = (idx & 31) * 4;
  int ci = m >> 5, cj = m & 31;
  float4 s = make_float4(0.f, 0.f, 0.f, 0.f);
  #pragma unroll
  for (int a = 0; a < 4; ++a)
    #pragma unroll
    for (int b = 0; b < 4; ++b)
      add4(s, x + ((4*ci + a) * 128 + 4*cj + b) * C_ + c4);
  s.x *= 0.0625f; s.y *= 0.0625f; s.z *= 0.0625f; s.w *= 0.0625f;
  *(float4*)(x1 + m * C_ + c4) = s;
}

__global__ void pool_e(const float* __restrict__ e, float* __restrict__ e1) {
  int idx = blockIdx.x * 256 + threadIdx.x;
  int combo = idx >> 5;
  int c4 = (idx & 31) * 4;
  int m = combo >> 2, dir = combo & 3;
  int ci = m >> 5, cj = m & 31;
  int cid, f0, fstep;
  if (dir == 0) { if (ci == 0) return;
    cid = cprefix(ci,cj);
    f0 = 48768 + (4*ci - 1) * 128 + 4*cj; fstep = 1;
  } else if (dir == 1) { if (cj == 0) return;
    cid = cprefix(ci,cj) + (ci>0);
    f0 = 16256 + (4*ci) * 127 + 4*cj - 1; fstep = 127;
  } else if (dir == 2) { if (cj == 31) return;
    cid = cprefix(ci,cj) + (ci>0) + (cj>0);
    f0 = (4*ci) * 127 + 4*cj + 3; fstep = 127;
  } else { if (ci == 31) return;
    cid = cprefix(ci,cj) + (ci>0) + (cj>0) + (cj<31);
    f0 = 32512 + (4*ci + 3) * 128 + 4*cj; fstep = 1;
  }
  float4 s = make_float4(0.f, 0.f, 0.f, 0.f);
  #pragma unroll
  for (int k = 0; k < 4; ++k)
    add4(s, e + (f0 + k * fstep) * C_ + c4);
  *(float4*)(e1 + cid * C_ + c4) = s;
}

__global__ void unpool_x(float* __restrict__ x, const float* __restrict__ x1,
                         const int* __restrict__ perm) {
  int idx = blockIdx.x * 256 + threadIdx.x;
  int n = idx >> 5, c4 = (idx & 31) * 4;
  int m = perm[n];
  float4 v = *(const float4*)(x + n * C_ + c4);
  add4(v, x1 + m * C_ + c4);
  *(float4*)(x + n * C_ + c4) = v;
}

__global__ void unpool_e(float* __restrict__ e, const float* __restrict__ e1,
                         const int* __restrict__ pe) {
  int idx = blockIdx.x * 256 + threadIdx.x;
  int k = idx >> 5, c4 = (idx & 31) * 4;
  int fe = pe[k];
  float4 v = *(const float4*)(e + fe * C_ + c4);
  add4(v, e1 + k * C_ + c4);
  *(float4*)(e + fe * C_ + c4) = v;
}

extern "C" void kernel_launch(void* const* d_in, const int* in_sizes, int n_in,
                              void* d_out, int out_size, void* d_ws, size_t ws_size,
                              hipStream_t stream) {
  const float* in_x  = (const float*)d_in[0];
  const float* in_ea = (const float*)d_in[1];
  const float* We1 = (const float*)d_in[2];
  const float* be1 = (const float*)d_in[3];
  const float* We2 = (const float*)d_in[4];
  const float* be2 = (const float*)d_in[5];
  const float* Wn1 = (const float*)d_in[6];
  const float* bn1 = (const float*)d_in[7];
  const float* Wn2 = (const float*)d_in[8];
  const float* bn2 = (const float*)d_in[9];
  const int* ei   = (const int*)d_in[10];
  const int* perm = (const int*)d_in[11];
  const int* pei  = (const int*)d_in[12];
  const int* pe   = (const int*)d_in[14];

  // outputs live in place
  float* x = (float*)d_out;             // N0 x 128
  float* e = x + (size_t)N0 * C_;       // E0 x 128
  // scratch in d_ws
  float* agg  = (float*)d_ws;           // N0 x 128
  float* x1   = agg + (size_t)N0 * C_;  // NC x 128
  float* e1   = x1 + (size_t)NC_ * C_;  // E1 x 128
  float* agg1 = e1 + (size_t)E1C * C_;  // NC x 128
  short* wsH  = (short*)(agg1 + (size_t)NC_ * C_);
  short* wsL  = wsH + W_TOTAL;

  hipMemcpyAsync(x, in_x, (size_t)N0 * C_ * 4, hipMemcpyDeviceToDevice, stream);
  hipMemcpyAsync(e, in_ea, (size_t)E0 * C_ * 4, hipMemcpyDeviceToDevice, stream);

  prep_weights<<<W_TOTAL / 256, 256, 0, stream>>>(We1, We2, Wn1, Wn2, wsH, wsL);

  const int* srcF = ei;  const int* dstF = ei + E0;
  const int* srcC = pei; const int* dstC = pei + E1C;

  #define WE1_OFF(l) (OFF_WE1 + (l) * 49152)
  #define WE2_OFF(l) (OFF_WE2 + (l) * 16384)
  #define WN1_OFF(l) (OFF_WN1 + (l) * 32768)
  #define WN2_OFF(l) (OFF_WN2 + (l) * 16384)

  for (int l = 0; l < 2; ++l) {
    mlp_mfma<0,128,2><<<E0/128, 256, 0, stream>>>(e, x, srcF, dstF,
        wsH + WE1_OFF(l), wsL + WE1_OFF(l), be1 + l*C_,
        wsH + WE2_OFF(l), wsL + WE2_OFF(l), be2 + l*C_);
    agg_fine<<<N0*32/256, 256, 0, stream>>>(e, agg);
    mlp_mfma<1,32,3><<<N0/32, 256, 0, stream>>>(x, agg, nullptr, nullptr,
        wsH + WN1_OFF(l), wsL + WN1_OFF(l), bn1 + l*C_,
        wsH + WN2_OFF(l), wsL + WN2_OFF(l), bn2 + l*C_);
  }

  pool_x<<<NC_*32/256, 256, 0, stream>>>(x, x1);
  pool_e<<<NC_*4*32/256, 256, 0, stream>>>(e, e1);

  for (int l = 2; l < 4; ++l) {
    mlp_mfma<0,32,3><<<E1C/32, 256, 0, stream>>>(e1, x1, srcC, dstC,
        wsH + WE1_OFF(l), wsL + WE1_OFF(l), be1 + l*C_,
        wsH + WE2_OFF(l), wsL + WE2_OFF(l), be2 + l*C_);
    agg_coarse<<<NC_*32/256, 256, 0, stream>>>(e1, agg1);
    mlp_mfma<1,32,3><<<NC_/32, 256, 0, stream>>>(x1, agg1, nullptr, nullptr,
        wsH + WN1_OFF(l), wsL + WN1_OFF(l), bn1 + l*C_,
        wsH + WN2_OFF(l), wsL + WN2_OFF(l), bn2 + l*C_);
  }

  unpool_x<<<N0*32/256, 256, 0, stream>>>(x, x1, perm);
  unpool_e<<<E1C*32/256, 256, 0, stream>>>(e, e1, pe);

  for (int l = 4; l < 6; ++l) {
    mlp_mfma<0,128,2><<<E0/128, 256, 0, stream>>>(e, x, srcF, dstF,
        wsH + WE1_OFF(l), wsL + WE1_OFF(l), be1 + l*C_,
        wsH + WE2_OFF(l), wsL + WE2_OFF(l), be2 + l*C_);
    agg_fine<<<N0*32/256, 256, 0, stream>>>(e, agg);
    mlp_mfma<1,32,3><<<N0/32, 256, 0, stream>>>(x, agg, nullptr, nullptr,
        wsH + WN1_OFF(l), wsL + WN1_OFF(l), bn1 + l*C_,
        wsH + WN2_OFF(l), wsL + WN2_OFF(l), bn2 + l*C_);
  }
}